// Round 2
// 468.701 us; speedup vs baseline: 1.0202x; 1.0202x over previous
//
#include <hip/hip_runtime.h>

typedef _Float16 half8 __attribute__((ext_vector_type(8)));
typedef _Float16 half4 __attribute__((ext_vector_type(4)));
typedef __fp16 fp16x2 __attribute__((ext_vector_type(2)));
typedef float floatx4 __attribute__((ext_vector_type(4)));

#define NB 8        // batches per block
#define SX 136      // X/Q/K/R row stride (fp16): 128 + 8 pad -> conflict-free b128 reads
#define SVT 72      // Vt row stride: 64 + 8 pad

// Convert [Wq|Wk|Wv|Wr] (each 128x128 fp32) into Wh[128][512] fp16 in workspace.
__global__ void wconv_kernel(const float* __restrict__ Wq, const float* __restrict__ Wk,
                             const float* __restrict__ Wv, const float* __restrict__ Wr,
                             _Float16* __restrict__ Wh) {
    int idx = blockIdx.x * 256 + threadIdx.x;   // 0 .. 65535
    int row = idx >> 9;
    int col = idx & 511;
    const float* s = (col < 128) ? Wq : (col < 256) ? Wk : (col < 384) ? Wv : Wr;
    Wh[idx] = (_Float16)s[row * 128 + (col & 127)];
}

__global__ __launch_bounds__(512, 2)
void autoint_kernel(const float* __restrict__ xg, const _Float16* __restrict__ Wh,
                    float* __restrict__ outg) {
    const int tid  = threadIdx.x;
    const int w    = tid >> 6;        // wave id 0..7
    const int lane = tid & 63;
    const int nn   = lane & 15;       // MFMA n / col-in-tile
    const int q    = lane >> 4;       // MFMA quad
    const int qp   = q & 1, qh = q >> 1;
    const long b0  = (long)blockIdx.x * NB;

    // 103 KB static LDS (1 block/CU — occupancy is register-capped at 2 waves/SIMD anyway)
    __shared__ _Float16 lds[52736];
    _Float16* Xs0 = lds;              // 64 x 136  (X double buffer, ping)
    _Float16* Xs1 = lds + 8704;       // 64 x 136  (pong)
    _Float16* Qs  = lds + 17408;      // 64 x 136
    _Float16* Ks  = lds + 26112;      // 64 x 136
    _Float16* Rs  = lds + 34816;      // 64 x 136
    _Float16* Vt  = lds + 43520;      // 128 x 72  (V transposed: [feature][key])

    // ---- hoist weight B-fragments: wave w owns col w*16+nn of each of Q/K/V/R ----
    half8 wf[4][4];
    #pragma unroll
    for (int g = 0; g < 4; ++g) {
        const int col = g * 128 + w * 16 + nn;
        #pragma unroll
        for (int ks = 0; ks < 4; ++ks) {
            half8 f;
            #pragma unroll
            for (int i = 0; i < 8; ++i)
                f[i] = Wh[(ks * 32 + q * 8 + i) * 512 + col];
            wf[g][ks] = f;
        }
    }

    // ---- prologue: stage X(b0) into Xs0 (all 512 threads, 4 float4 each) ----
    float4 pf[4];
    {
        const float4* Xg = (const float4*)(xg + b0 * 8192);
        #pragma unroll
        for (int t = 0; t < 4; ++t) pf[t] = Xg[t * 512 + tid];
        #pragma unroll
        for (int t = 0; t < 4; ++t) {
            int g = t * 512 + tid;
            int row = g >> 5, c4 = (g & 31) * 4;
            half4 h = { (_Float16)pf[t].x, (_Float16)pf[t].y,
                        (_Float16)pf[t].z, (_Float16)pf[t].w };
            *(half4*)(Xs0 + row * SX + c4) = h;
        }
    }
    __syncthreads();

    #pragma unroll 2
    for (int it = 0; it < NB; ++it) {
        const long b = b0 + it;
        const _Float16* Xc = (it & 1) ? Xs1 : Xs0;
        _Float16*       Xn = (it & 1) ? Xs0 : Xs1;

        // prefetch next batch's X (lands under the projection MFMAs)
        if (it + 1 < NB) {
            const float4* Xg = (const float4*)(xg + (b + 1) * 8192);
            #pragma unroll
            for (int t = 0; t < 4; ++t) pf[t] = Xg[t * 512 + tid];
        }

        // ---- phase 1: projections  C(64x512) = X(64x128) @ [Wq|Wk|Wv|Wr] ----
        floatx4 acc[4][4];
        {
            floatx4 z = {0.f, 0.f, 0.f, 0.f};
            #pragma unroll
            for (int rt = 0; rt < 4; ++rt)
                #pragma unroll
                for (int g = 0; g < 4; ++g) acc[rt][g] = z;
        }
        #pragma unroll
        for (int ks = 0; ks < 4; ++ks) {
            half8 a[4];
            #pragma unroll
            for (int rt = 0; rt < 4; ++rt)
                a[rt] = *(const half8*)(Xc + (rt * 16 + nn) * SX + ks * 32 + q * 8);
            #pragma unroll
            for (int rt = 0; rt < 4; ++rt)
                #pragma unroll
                for (int g = 0; g < 4; ++g)
                    acc[rt][g] = __builtin_amdgcn_mfma_f32_16x16x32_f16(
                        a[rt], wf[g][ks], acc[rt][g], 0, 0, 0);
        }

        // ---- scatter Q, K, V^T, R (every wave scatters its own 4 col tiles) ----
        const int fc = w * 16 + nn;
        #pragma unroll
        for (int rt = 0; rt < 4; ++rt) {
            const int r0 = rt * 16 + q * 4;
            #pragma unroll
            for (int r = 0; r < 4; ++r) Qs[(r0 + r) * SX + fc] = (_Float16)acc[rt][0][r];
            #pragma unroll
            for (int r = 0; r < 4; ++r) Ks[(r0 + r) * SX + fc] = (_Float16)acc[rt][1][r];
            half4 hv = { (_Float16)acc[rt][2][0], (_Float16)acc[rt][2][1],
                         (_Float16)acc[rt][2][2], (_Float16)acc[rt][2][3] };
            *(half4*)(Vt + fc * SVT + r0) = hv;                 // keys contiguous
            #pragma unroll
            for (int r = 0; r < 4; ++r) Rs[(r0 + r) * SX + fc] = (_Float16)acc[rt][3][r];
        }

        // ---- write prefetched X(b+1) into the other X buffer (no extra barrier) ----
        if (it + 1 < NB) {
            #pragma unroll
            for (int t = 0; t < 4; ++t) {
                int g = t * 512 + tid;
                int row = g >> 5, c4 = (g & 31) * 4;
                half4 h = { (_Float16)pf[t].x, (_Float16)pf[t].y,
                            (_Float16)pf[t].z, (_Float16)pf[t].w };
                *(half4*)(Xn + row * SX + c4) = h;
            }
        }

        __syncthreads();   // B1: Q/K/V/R(b) visible, Xs(b+1) staged

        // ---- phase 2 (ALL waves): S' = K Q^T, in-register softmax, PV, epilogue ----
        // wave w owns score rows mt*16..mt*16+15 and output col half eb*16..eb*16+63
        const int mt = w & 3;
        const int eb = (w >> 2) * 4;

        floatx4 sacc[4];
        {
            floatx4 z = {0.f, 0.f, 0.f, 0.f};
            #pragma unroll
            for (int nt = 0; nt < 4; ++nt) sacc[nt] = z;
        }
        #pragma unroll
        for (int ks = 0; ks < 4; ++ks) {
            half8 bq = *(const half8*)(Qs + (mt * 16 + nn) * SX + ks * 32 + q * 8);
            #pragma unroll
            for (int nt = 0; nt < 4; ++nt) {
                half8 ak = *(const half8*)(Ks + (nt * 16 + nn) * SX + ks * 32 + q * 8);
                // S'[nt*16+q*4+r][mt*16+nn] = S[m=mt*16+nn][n=nt*16+q*4+r]
                sacc[nt] = __builtin_amdgcn_mfma_f32_16x16x32_f16(ak, bq, sacc[nt], 0, 0, 0);
            }
        }

        // softmax of row m = mt*16+nn: 16 in-lane values + reduce across the q-quad
        float mx = sacc[0][0];
        #pragma unroll
        for (int nt = 0; nt < 4; ++nt)
            #pragma unroll
            for (int r = 0; r < 4; ++r) mx = fmaxf(mx, sacc[nt][r]);
        mx = fmaxf(mx, __shfl_xor(mx, 16));
        mx = fmaxf(mx, __shfl_xor(mx, 32));
        float ex[4][4];
        float sum = 0.f;
        #pragma unroll
        for (int nt = 0; nt < 4; ++nt)
            #pragma unroll
            for (int r = 0; r < 4; ++r) {
                ex[nt][r] = __expf(sacc[nt][r] - mx);
                sum += ex[nt][r];
            }
        sum += __shfl_xor(sum, 16);
        sum += __shfl_xor(sum, 32);
        const float inv = 1.0f / sum;

        // pack P to fp16 pairs: pku[nt][h] = {P[n=nt*16+q*4+2h], P[n=..+2h+1]}
        unsigned pku[4][2];
        #pragma unroll
        for (int nt = 0; nt < 4; ++nt)
            #pragma unroll
            for (int h = 0; h < 2; ++h) {
                union { fp16x2 h2; unsigned u; } cv;
                cv.h2 = __builtin_amdgcn_cvt_pkrtz(ex[nt][2 * h] * inv, ex[nt][2 * h + 1] * inv);
                pku[nt][h] = cv.u;
            }

        // redistribute P into MFMA A-fragments: af[ks][k=q*8..q*8+7] via 8 shfls.
        // call c: ks=(c>>1)&1, h=c&1, lo=c>>2; source lane passes pk[2ks+(qp^lo)][h];
        // reader pulls from lane ((qp*2+(qh^lo))*16+nn); lands at t=h+2*(qh^lo).
        unsigned af2[2][4];
        #pragma unroll
        for (int c = 0; c < 8; ++c) {
            const int ks2 = (c >> 1) & 1;
            const int h   = c & 1;
            const int lo  = c >> 2;
            unsigned gv = (qp ^ lo) ? pku[2 * ks2 + 1][h] : pku[2 * ks2][h];
            int srcl = ((qp << 1) + (qh ^ lo)) * 16 + nn;
            af2[ks2][h + 2 * lo] = (unsigned)__shfl((int)gv, srcl);
        }
        #pragma unroll
        for (int ks2 = 0; ks2 < 2; ++ks2) {   // lanes with qh==1 have halves swapped
            unsigned a0 = af2[ks2][0], a1 = af2[ks2][1], a2 = af2[ks2][2], a3 = af2[ks2][3];
            af2[ks2][0] = qh ? a2 : a0;
            af2[ks2][1] = qh ? a3 : a1;
            af2[ks2][2] = qh ? a0 : a2;
            af2[ks2][3] = qh ? a1 : a3;
        }
        half8 af[2];
        #pragma unroll
        for (int ks2 = 0; ks2 < 2; ++ks2) {
            union { unsigned u[4]; half8 h; } uu;
            uu.u[0] = af2[ks2][0]; uu.u[1] = af2[ks2][1];
            uu.u[2] = af2[ks2][2]; uu.u[3] = af2[ks2][3];
            af[ks2] = uu.h;
        }

        // PV: new_e[mt rows][eb..eb+3 col tiles], P stays in registers
        floatx4 pv[4];
        {
            floatx4 z = {0.f, 0.f, 0.f, 0.f};
            #pragma unroll
            for (int cc = 0; cc < 4; ++cc) pv[cc] = z;
        }
        #pragma unroll
        for (int ks2 = 0; ks2 < 2; ++ks2)
            #pragma unroll
            for (int cc = 0; cc < 4; ++cc) {
                half8 bv = *(const half8*)(Vt + ((eb + cc) * 16 + nn) * SVT + ks2 * 32 + q * 8);
                pv[cc] = __builtin_amdgcn_mfma_f32_16x16x32_f16(af[ks2], bv, pv[cc], 0, 0, 0);
            }

        // fused epilogue: relu(R + new_e)
        float* ob = outg + b * 8192;
        #pragma unroll
        for (int cc = 0; cc < 4; ++cc) {
            const int col = (eb + cc) * 16 + nn;
            #pragma unroll
            for (int r = 0; r < 4; ++r) {
                const int row = mt * 16 + q * 4 + r;
                float rv = (float)Rs[row * SX + col];
                ob[row * 128 + col] = fmaxf(rv + pv[cc][r], 0.0f);
            }
        }

        __syncthreads();   // B2: Q/K/V/R free for next batch's scatter
    }
}

extern "C" void kernel_launch(void* const* d_in, const int* in_sizes, int n_in,
                              void* d_out, int out_size, void* d_ws, size_t ws_size,
                              hipStream_t stream) {
    const float* x  = (const float*)d_in[0];
    const float* Wq = (const float*)d_in[1];
    const float* Wk = (const float*)d_in[2];
    const float* Wv = (const float*)d_in[3];
    const float* Wr = (const float*)d_in[4];
    _Float16* Wh = (_Float16*)d_ws;      // 128x512 fp16 = 128 KB scratch
    float* out = (float*)d_out;

    wconv_kernel<<<256, 256, 0, stream>>>(Wq, Wk, Wv, Wr, Wh);
    autoint_kernel<<<1024, 512, 0, stream>>>(x, Wh, out);
}